// Round 1
// baseline (528.564 us; speedup 1.0000x reference)
//
#include <hip/hip_runtime.h>

#define PITCH 72  // 64 + 8 bf16 pad: row stride 144B = 36 banks -> only free 2-way conflicts

typedef __attribute__((ext_vector_type(8))) short bf16x8;
typedef __attribute__((ext_vector_type(4))) float f32x4;
typedef __attribute__((ext_vector_type(8))) unsigned short u16x8;

__device__ __forceinline__ unsigned short f2bf(float f) {
  union { float f; unsigned int u; } v; v.f = f;
  unsigned int u = v.u + 0x7fffu + ((v.u >> 16) & 1u);  // round-nearest-even
  return (unsigned short)(u >> 16);
}

__device__ __forceinline__ f32x4 mfma16(bf16x8 a, bf16x8 b, f32x4 c) {
  return __builtin_amdgcn_mfma_f32_16x16x32_bf16(a, b, c, 0, 0, 0);
}

// ---------------------------------------------------------------------------
// Kernel 1: fused QKV projection.  x[16384,1024] fp32 @ W{q,k,v}[64,1024]^T.
// Outputs bf16: q_ws[t][h] (pre-scaled by 1/8), k_ws[t][h], vT_ws[b][h][t].
// WG tile: 64 M-rows x 192 N-cols, 4 waves (16 rows each), BK=64.
// ---------------------------------------------------------------------------
__global__ __launch_bounds__(256) void qkv_kernel(
    const float* __restrict__ x, const float* __restrict__ Wq,
    const float* __restrict__ Wk, const float* __restrict__ Wv,
    unsigned short* __restrict__ q_ws, unsigned short* __restrict__ k_ws,
    unsigned short* __restrict__ vT_ws) {
  __shared__ unsigned short Xs[64 * PITCH];
  __shared__ unsigned short Ws[192 * PITCH];

  const int tid = threadIdx.x;
  const int wave = tid >> 6, lane = tid & 63;
  const int quad = lane >> 4, l16 = lane & 15;
  const int m0 = blockIdx.x * 64;

  f32x4 acc[12];
#pragma unroll
  for (int i = 0; i < 12; ++i) acc[i] = (f32x4)0.0f;

  for (int k0 = 0; k0 < 1024; k0 += 64) {
    // stage X tile 64x64 fp32 -> bf16 LDS
#pragma unroll
    for (int i = 0; i < 4; ++i) {
      int cc = tid + i * 256;
      int row = cc >> 4, c4 = cc & 15;
      float4 f = *(const float4*)(x + (size_t)(m0 + row) * 1024 + k0 + c4 * 4);
      unsigned short h0 = f2bf(f.x), h1 = f2bf(f.y), h2 = f2bf(f.z), h3 = f2bf(f.w);
      ushort4 h = make_ushort4(h0, h1, h2, h3);
      *(ushort4*)&Xs[row * PITCH + c4 * 4] = h;
    }
    // stage W slab 192x64 fp32 -> bf16 LDS (rows 0-63 Wq, 64-127 Wk, 128-191 Wv)
#pragma unroll
    for (int i = 0; i < 12; ++i) {
      int cc = tid + i * 256;
      int row = cc >> 4, c4 = cc & 15;
      int which = row >> 6, wrow = row & 63;
      const float* wp = (which == 0) ? Wq : ((which == 1) ? Wk : Wv);
      float4 f = *(const float4*)(wp + (size_t)wrow * 1024 + k0 + c4 * 4);
      ushort4 h = make_ushort4(f2bf(f.x), f2bf(f.y), f2bf(f.z), f2bf(f.w));
      *(ushort4*)&Ws[row * PITCH + c4 * 4] = h;
    }
    __syncthreads();
#pragma unroll
    for (int ks = 0; ks < 64; ks += 32) {
      bf16x8 a = *(const bf16x8*)&Xs[(wave * 16 + l16) * PITCH + ks + quad * 8];
#pragma unroll
      for (int nt = 0; nt < 12; ++nt) {
        bf16x8 b = *(const bf16x8*)&Ws[(nt * 16 + l16) * PITCH + ks + quad * 8];
        acc[nt] = mfma16(a, b, acc[nt]);
      }
    }
    __syncthreads();
  }

  // epilogue: C/D layout row = quad*4+reg, col = l16 (within 16x16 tile)
  const int mrow = wave * 16 + quad * 4;
  // q (tiles 0..3): pre-scale by 1/sqrt(64) = 0.125
#pragma unroll
  for (int nt = 0; nt < 4; ++nt)
#pragma unroll
    for (int r = 0; r < 4; ++r) {
      int m = m0 + mrow + r;
      int h = nt * 16 + l16;
      q_ws[(size_t)m * 64 + h] = f2bf(acc[nt][r] * 0.125f);
    }
  // k (tiles 4..7)
#pragma unroll
  for (int nt = 0; nt < 4; ++nt)
#pragma unroll
    for (int r = 0; r < 4; ++r) {
      int m = m0 + mrow + r;
      int h = nt * 16 + l16;
      k_ws[(size_t)m * 64 + h] = f2bf(acc[nt + 4][r]);
    }
  // v (tiles 8..11): transpose via LDS (reuse Xs), store vT[b][h][t] coalesced
  __syncthreads();
#pragma unroll
  for (int nt = 0; nt < 4; ++nt)
#pragma unroll
    for (int r = 0; r < 4; ++r)
      Xs[(nt * 16 + l16) * PITCH + mrow + r] = f2bf(acc[nt + 8][r]);
  __syncthreads();
  const int b = m0 >> 12, t0 = m0 & 4095;
#pragma unroll
  for (int i = 0; i < 2; ++i) {
    int cc = tid + i * 256;
    int h = cc >> 3, c8 = cc & 7;
    u16x8 v = *(const u16x8*)&Xs[h * PITCH + c8 * 8];
    *(u16x8*)(vT_ws + ((size_t)b * 64 + h) * 4096 + t0 + c8 * 8) = v;
  }
}

// ---------------------------------------------------------------------------
// Kernel 2: attention. One WG per (batch, 64 q-rows). 4 waves x 16 q-rows.
// Pass 1: S=QK^T (q pre-scaled), e=exp(S) -> rowsums S,W and O += P.V (P via
// per-wave LDS round-trip). Pass 2: recompute S, write attn = e/S.
// Entropy per row = log(S) - W/S; WG partial atomicAdd'ed to entAcc.
// ---------------------------------------------------------------------------
__global__ __launch_bounds__(256) void attn_kernel(
    const unsigned short* __restrict__ q_ws, const unsigned short* __restrict__ k_ws,
    const unsigned short* __restrict__ vT_ws, float* __restrict__ out,
    float* __restrict__ attn, float* __restrict__ entAcc) {
  __shared__ unsigned short Qs[64 * PITCH];
  __shared__ unsigned short Ks[64 * PITCH];
  __shared__ unsigned short Vts[64 * PITCH];
  __shared__ unsigned short Ps[4][16 * PITCH];
  __shared__ float rowS[64], rowW[64], invS[64];

  const int tid = threadIdx.x;
  const int wave = tid >> 6, lane = tid & 63;
  const int quad = lane >> 4, l16 = lane & 15;
  const int bx = blockIdx.x;
  const int b = bx >> 6, q0 = (bx & 63) * 64;

  const unsigned short* qb = q_ws + ((size_t)b * 4096 + q0) * 64;
  const unsigned short* kb = k_ws + (size_t)b * 4096 * 64;
  const unsigned short* vtb = vT_ws + (size_t)b * 64 * 4096;

  // load Q tile once
#pragma unroll
  for (int i = 0; i < 2; ++i) {
    int cc = tid + i * 256;
    int row = cc >> 3, c8 = cc & 7;
    *(u16x8*)&Qs[row * PITCH + c8 * 8] = *(const u16x8*)(qb + (size_t)row * 64 + c8 * 8);
  }

  f32x4 Oacc[4];
#pragma unroll
  for (int i = 0; i < 4; ++i) Oacc[i] = (f32x4)0.0f;
  float sumE[4] = {0.f, 0.f, 0.f, 0.f};
  float sumES[4] = {0.f, 0.f, 0.f, 0.f};

  __syncthreads();

  // ---- pass 1 ----
  for (int kt = 0; kt < 64; ++kt) {
    const int k0 = kt * 64;
#pragma unroll
    for (int i = 0; i < 2; ++i) {
      int cc = tid + i * 256;
      int row = cc >> 3, c8 = cc & 7;
      *(u16x8*)&Ks[row * PITCH + c8 * 8] =
          *(const u16x8*)(kb + (size_t)(k0 + row) * 64 + c8 * 8);
      *(u16x8*)&Vts[row * PITCH + c8 * 8] =
          *(const u16x8*)(vtb + (size_t)row * 4096 + k0 + c8 * 8);
    }
    __syncthreads();

    f32x4 s[4];
#pragma unroll
    for (int i = 0; i < 4; ++i) s[i] = (f32x4)0.0f;
#pragma unroll
    for (int ks = 0; ks < 64; ks += 32) {
      bf16x8 a = *(const bf16x8*)&Qs[(wave * 16 + l16) * PITCH + ks + quad * 8];
#pragma unroll
      for (int nt = 0; nt < 4; ++nt) {
        bf16x8 bk = *(const bf16x8*)&Ks[(nt * 16 + l16) * PITCH + ks + quad * 8];
        s[nt] = mfma16(a, bk, s[nt]);
      }
    }
    // exp + accumulate row stats + stash P (bf16) in per-wave LDS
#pragma unroll
    for (int nt = 0; nt < 4; ++nt)
#pragma unroll
      for (int r = 0; r < 4; ++r) {
        float sv = s[nt][r];
        float e = __expf(sv);
        sumE[r] += e;
        sumES[r] += e * sv;
        Ps[wave][(quad * 4 + r) * PITCH + nt * 16 + l16] = f2bf(e);
      }
    // O += P.V (wave-private P; compiler inserts lgkmcnt waits for LDS deps)
#pragma unroll
    for (int kk = 0; kk < 64; kk += 32) {
      bf16x8 a = *(const bf16x8*)&Ps[wave][l16 * PITCH + kk + quad * 8];
#pragma unroll
      for (int ht = 0; ht < 4; ++ht) {
        bf16x8 bv = *(const bf16x8*)&Vts[(ht * 16 + l16) * PITCH + kk + quad * 8];
        Oacc[ht] = mfma16(a, bv, Oacc[ht]);
      }
    }
    __syncthreads();
  }

  // ---- row reductions: 16-lane butterfly within each quad-row group ----
#pragma unroll
  for (int off = 1; off < 16; off <<= 1)
#pragma unroll
    for (int r = 0; r < 4; ++r) {
      sumE[r] += __shfl_xor(sumE[r], off, 64);
      sumES[r] += __shfl_xor(sumES[r], off, 64);
    }
  if (l16 == 0)
#pragma unroll
    for (int r = 0; r < 4; ++r) {
      rowS[wave * 16 + quad * 4 + r] = sumE[r];
      rowW[wave * 16 + quad * 4 + r] = sumES[r];
    }
  __syncthreads();
  if (tid < 64) {  // exactly wave 0
    float S = rowS[tid], W = rowW[tid];
    float inv = 1.0f / S;
    invS[tid] = inv;
    float ent = __logf(S) - W * inv;  // -sum p log p, closed form
#pragma unroll
    for (int off = 1; off < 64; off <<= 1) ent += __shfl_xor(ent, off, 64);
    if (tid == 0) atomicAdd(entAcc, ent);
  }
  __syncthreads();

  float invR[4];
#pragma unroll
  for (int r = 0; r < 4; ++r) invR[r] = invS[wave * 16 + quad * 4 + r];

  // write out = Oacc / S
#pragma unroll
  for (int ht = 0; ht < 4; ++ht)
#pragma unroll
    for (int r = 0; r < 4; ++r) {
      int m = q0 + wave * 16 + quad * 4 + r;
      out[((size_t)b * 4096 + m) * 64 + ht * 16 + l16] = Oacc[ht][r] * invR[r];
    }

  // ---- pass 2: recompute scores, write normalized attn ----
  float* attnb = attn + (size_t)b * 4096 * 4096;
  for (int kt = 0; kt < 64; ++kt) {
    const int k0 = kt * 64;
    __syncthreads();
#pragma unroll
    for (int i = 0; i < 2; ++i) {
      int cc = tid + i * 256;
      int row = cc >> 3, c8 = cc & 7;
      *(u16x8*)&Ks[row * PITCH + c8 * 8] =
          *(const u16x8*)(kb + (size_t)(k0 + row) * 64 + c8 * 8);
    }
    __syncthreads();

    f32x4 s[4];
#pragma unroll
    for (int i = 0; i < 4; ++i) s[i] = (f32x4)0.0f;
#pragma unroll
    for (int ks = 0; ks < 64; ks += 32) {
      bf16x8 a = *(const bf16x8*)&Qs[(wave * 16 + l16) * PITCH + ks + quad * 8];
#pragma unroll
      for (int nt = 0; nt < 4; ++nt) {
        bf16x8 bk = *(const bf16x8*)&Ks[(nt * 16 + l16) * PITCH + ks + quad * 8];
        s[nt] = mfma16(a, bk, s[nt]);
      }
    }
#pragma unroll
    for (int nt = 0; nt < 4; ++nt)
#pragma unroll
      for (int r = 0; r < 4; ++r) {
        float p = __expf(s[nt][r]) * invR[r];
        attnb[(size_t)(q0 + wave * 16 + quad * 4 + r) * 4096 + k0 + nt * 16 + l16] = p;
      }
  }
}

// ---------------------------------------------------------------------------
// Kernel 3: new_energy = 0.9*energy + 0.1*mean_entropy
// ---------------------------------------------------------------------------
__global__ void energy_kernel(const float* __restrict__ energy,
                              const float* __restrict__ entAcc,
                              float* __restrict__ dst) {
  if (threadIdx.x == 0 && blockIdx.x == 0)
    dst[0] = 0.9f * energy[0] + 0.1f * (entAcc[0] * (1.0f / 16384.0f));
}

extern "C" void kernel_launch(void* const* d_in, const int* in_sizes, int n_in,
                              void* d_out, int out_size, void* d_ws, size_t ws_size,
                              hipStream_t stream) {
  (void)in_sizes; (void)n_in; (void)out_size; (void)ws_size;
  const float* x = (const float*)d_in[0];
  const float* Wq = (const float*)d_in[1];
  const float* Wk = (const float*)d_in[2];
  const float* Wv = (const float*)d_in[3];
  const float* energy = (const float*)d_in[4];

  float* out = (float*)d_out;                        // [4,4096,64]
  float* attn = out + (size_t)4 * 4096 * 64;         // [4,4096,4096]
  float* dst_energy = attn + (size_t)4 * 4096 * 4096;  // scalar

  char* ws = (char*)d_ws;
  float* entAcc = (float*)ws;
  unsigned short* q_ws = (unsigned short*)(ws + 256);
  unsigned short* k_ws = q_ws + (size_t)16384 * 64;
  unsigned short* vT_ws = k_ws + (size_t)16384 * 64;

  hipMemsetAsync(entAcc, 0, sizeof(float), stream);
  qkv_kernel<<<256, 256, 0, stream>>>(x, Wq, Wk, Wv, q_ws, k_ws, vT_ws);
  attn_kernel<<<256, 256, 0, stream>>>(q_ws, k_ws, vT_ws, out, attn, entAcc);
  energy_kernel<<<1, 64, 0, stream>>>(energy, entAcc, dst_energy);
}

// Round 2
// 440.623 us; speedup vs baseline: 1.1996x; 1.1996x over previous
//
#include <hip/hip_runtime.h>

#define PITCH 72   // 64+8 bf16 pad for 64-col tiles
#define PPITCH 68  // P-scratch pitch: (4q+r)*34 mod 32 = 8q+2r -> conflict-free quads

typedef __attribute__((ext_vector_type(8))) short bf16x8;
typedef __attribute__((ext_vector_type(4))) float f32x4;
typedef __attribute__((ext_vector_type(8))) unsigned short u16x8;

__device__ __forceinline__ unsigned short f2bf(float f) {
  union { float f; unsigned int u; } v; v.f = f;
  unsigned int u = v.u + 0x7fffu + ((v.u >> 16) & 1u);  // RNE
  return (unsigned short)(u >> 16);
}

__device__ __forceinline__ f32x4 mfma16(bf16x8 a, bf16x8 b, f32x4 c) {
  return __builtin_amdgcn_mfma_f32_16x16x32_bf16(a, b, c, 0, 0, 0);
}

// ---------------------------------------------------------------------------
// Kernel 1: QKV projection, one WG per (m-tile, which) -> grid 768.
// Each WG: 64 rows x 64 cols of one projection, K=1024, 4 waves x 16 rows.
// ---------------------------------------------------------------------------
__global__ __launch_bounds__(256) void qkv_kernel(
    const float* __restrict__ x, const float* __restrict__ Wq,
    const float* __restrict__ Wk, const float* __restrict__ Wv,
    unsigned short* __restrict__ q_ws, unsigned short* __restrict__ k_ws,
    unsigned short* __restrict__ vT_ws) {
  __shared__ unsigned short Xs[64 * PITCH];
  __shared__ unsigned short Ws[64 * PITCH];

  const int tid = threadIdx.x;
  const int wave = tid >> 6, lane = tid & 63;
  const int quad = lane >> 4, l16 = lane & 15;
  const int bx = blockIdx.x;
  const int mt = bx / 3, which = bx - mt * 3;  // consecutive bx share x tile (L2)
  const int m0 = mt * 64;
  const float* wp = (which == 0) ? Wq : ((which == 1) ? Wk : Wv);

  f32x4 acc[4];
#pragma unroll
  for (int i = 0; i < 4; ++i) acc[i] = (f32x4)0.0f;

  const int srow = tid >> 4, sc4 = tid & 15;  // staging coords: 4 f4/thread row-split
  for (int k0 = 0; k0 < 1024; k0 += 64) {
#pragma unroll
    for (int i = 0; i < 4; ++i) {
      int row = srow + i * 16;
      float4 f = *(const float4*)(x + (size_t)(m0 + row) * 1024 + k0 + sc4 * 4);
      *(ushort4*)&Xs[row * PITCH + sc4 * 4] =
          make_ushort4(f2bf(f.x), f2bf(f.y), f2bf(f.z), f2bf(f.w));
      float4 g = *(const float4*)(wp + (size_t)row * 1024 + k0 + sc4 * 4);
      *(ushort4*)&Ws[row * PITCH + sc4 * 4] =
          make_ushort4(f2bf(g.x), f2bf(g.y), f2bf(g.z), f2bf(g.w));
    }
    __syncthreads();
#pragma unroll
    for (int ks = 0; ks < 64; ks += 32) {
      bf16x8 a = *(const bf16x8*)&Xs[(wave * 16 + l16) * PITCH + ks + quad * 8];
#pragma unroll
      for (int nt = 0; nt < 4; ++nt) {
        bf16x8 b = *(const bf16x8*)&Ws[(nt * 16 + l16) * PITCH + ks + quad * 8];
        acc[nt] = mfma16(a, b, acc[nt]);
      }
    }
    __syncthreads();
  }

  const int mrow = wave * 16 + quad * 4;  // C/D: row=quad*4+r, col=l16
  if (which == 0) {
#pragma unroll
    for (int nt = 0; nt < 4; ++nt)
#pragma unroll
      for (int r = 0; r < 4; ++r)
        q_ws[(size_t)(m0 + mrow + r) * 64 + nt * 16 + l16] = f2bf(acc[nt][r] * 0.125f);
  } else if (which == 1) {
#pragma unroll
    for (int nt = 0; nt < 4; ++nt)
#pragma unroll
      for (int r = 0; r < 4; ++r)
        k_ws[(size_t)(m0 + mrow + r) * 64 + nt * 16 + l16] = f2bf(acc[nt][r]);
  } else {
    // transpose v via LDS (Xs reusable: trailing barrier above), store vT[b][h][t]
#pragma unroll
    for (int nt = 0; nt < 4; ++nt)
#pragma unroll
      for (int r = 0; r < 4; ++r)
        Xs[(nt * 16 + l16) * PITCH + mrow + r] = f2bf(acc[nt + 0][r]);  // acc holds v
    __syncthreads();
    const int b = m0 >> 12, t0 = m0 & 4095;
#pragma unroll
    for (int i = 0; i < 2; ++i) {
      int cc = tid + i * 256;
      int h = cc >> 3, c8 = cc & 7;
      u16x8 v = *(const u16x8*)&Xs[h * PITCH + c8 * 8];
      *(u16x8*)(vT_ws + ((size_t)b * 64 + h) * 4096 + t0 + c8 * 8) = v;
    }
  }
}

// ---------------------------------------------------------------------------
// Kernel 2: flash partials. Grid 1024 = (b, qtile, ksplit of 4). Each WG:
// 64 q-rows x 1024 keys -> partial Opart[64][64], Spart[64], Wpart[64].
// No max-subtraction (scores ~N(0,1)) -> stats are additive over K-splits.
// ---------------------------------------------------------------------------
__global__ __launch_bounds__(256) void flash_kernel(
    const unsigned short* __restrict__ q_ws, const unsigned short* __restrict__ k_ws,
    const unsigned short* __restrict__ vT_ws, float* __restrict__ Opart,
    float* __restrict__ Spart, float* __restrict__ Wpart) {
  __shared__ unsigned short Qs[64 * PITCH];
  __shared__ unsigned short Ks[64 * PITCH];
  __shared__ unsigned short Vts[64 * PITCH];
  __shared__ unsigned short Ps[4][16 * PPITCH];

  const int tid = threadIdx.x;
  const int wave = tid >> 6, lane = tid & 63;
  const int quad = lane >> 4, l16 = lane & 15;
  const int bx = blockIdx.x;
  const int ksp = bx & 3, qt = (bx >> 2) & 63, b = bx >> 8;
  const int q0 = qt * 64;

  const unsigned short* qb = q_ws + ((size_t)b * 4096 + q0) * 64;
  const unsigned short* kb = k_ws + (size_t)b * 4096 * 64;
  const unsigned short* vtb = vT_ws + (size_t)b * 64 * 4096;

#pragma unroll
  for (int i = 0; i < 2; ++i) {
    int cc = tid + i * 256;
    int row = cc >> 3, c8 = cc & 7;
    *(u16x8*)&Qs[row * PITCH + c8 * 8] = *(const u16x8*)(qb + (size_t)row * 64 + c8 * 8);
  }

  f32x4 Oacc[4];
#pragma unroll
  for (int i = 0; i < 4; ++i) Oacc[i] = (f32x4)0.0f;
  float sumE[4] = {0.f, 0.f, 0.f, 0.f};
  float sumES[4] = {0.f, 0.f, 0.f, 0.f};

  __syncthreads();

  for (int kt = ksp * 16; kt < ksp * 16 + 16; ++kt) {
    const int k0 = kt * 64;
#pragma unroll
    for (int i = 0; i < 2; ++i) {
      int cc = tid + i * 256;
      int row = cc >> 3, c8 = cc & 7;
      *(u16x8*)&Ks[row * PITCH + c8 * 8] =
          *(const u16x8*)(kb + (size_t)(k0 + row) * 64 + c8 * 8);
      *(u16x8*)&Vts[row * PITCH + c8 * 8] =
          *(const u16x8*)(vtb + (size_t)row * 4096 + k0 + c8 * 8);
    }
    __syncthreads();

    f32x4 s[4];
#pragma unroll
    for (int i = 0; i < 4; ++i) s[i] = (f32x4)0.0f;
#pragma unroll
    for (int ks = 0; ks < 64; ks += 32) {
      bf16x8 a = *(const bf16x8*)&Qs[(wave * 16 + l16) * PITCH + ks + quad * 8];
#pragma unroll
      for (int nt = 0; nt < 4; ++nt) {
        bf16x8 bk = *(const bf16x8*)&Ks[(nt * 16 + l16) * PITCH + ks + quad * 8];
        s[nt] = mfma16(a, bk, s[nt]);
      }
    }
#pragma unroll
    for (int nt = 0; nt < 4; ++nt)
#pragma unroll
      for (int r = 0; r < 4; ++r) {
        float sv = s[nt][r];
        float e = __expf(sv);
        sumE[r] += e;
        sumES[r] += e * sv;
        Ps[wave][(quad * 4 + r) * PPITCH + nt * 16 + l16] = f2bf(e);
      }
#pragma unroll
    for (int kk = 0; kk < 64; kk += 32) {
      bf16x8 a = *(const bf16x8*)&Ps[wave][l16 * PPITCH + kk + quad * 8];
#pragma unroll
      for (int ht = 0; ht < 4; ++ht) {
        bf16x8 bv = *(const bf16x8*)&Vts[(ht * 16 + l16) * PITCH + kk + quad * 8];
        Oacc[ht] = mfma16(a, bv, Oacc[ht]);
      }
    }
    __syncthreads();
  }

  // reduce row stats over the 16 l16-lanes (offsets <16 stay within quad)
#pragma unroll
  for (int off = 1; off < 16; off <<= 1)
#pragma unroll
    for (int r = 0; r < 4; ++r) {
      sumE[r] += __shfl_xor(sumE[r], off, 64);
      sumES[r] += __shfl_xor(sumES[r], off, 64);
    }
  const int mrow = wave * 16 + quad * 4;
  if (l16 == 0)
#pragma unroll
    for (int r = 0; r < 4; ++r) {
      Spart[(size_t)bx * 64 + mrow + r] = sumE[r];
      Wpart[(size_t)bx * 64 + mrow + r] = sumES[r];
    }
  float* Op = Opart + (size_t)bx * 4096;
#pragma unroll
  for (int ht = 0; ht < 4; ++ht)
#pragma unroll
    for (int r = 0; r < 4; ++r)
      Op[(size_t)(mrow + r) * 64 + ht * 16 + l16] = Oacc[ht][r];
}

// ---------------------------------------------------------------------------
// Kernel 3: combine partials -> out, invS, entropy atomicAdd. Grid 256.
// ---------------------------------------------------------------------------
__global__ __launch_bounds__(256) void combine_kernel(
    const float* __restrict__ Opart, const float* __restrict__ Spart,
    const float* __restrict__ Wpart, float* __restrict__ out,
    float* __restrict__ invS, float* __restrict__ entAcc) {
  __shared__ float invLds[64];
  const int tid = threadIdx.x;
  const int bx = blockIdx.x;  // = b*64 + qt; flat row0 = bx*64

  if (tid < 64) {
    float S = 0.f, W = 0.f;
#pragma unroll
    for (int ks = 0; ks < 4; ++ks) {
      S += Spart[(size_t)(bx * 4 + ks) * 64 + tid];
      W += Wpart[(size_t)(bx * 4 + ks) * 64 + tid];
    }
    float inv = 1.0f / S;
    invS[(size_t)bx * 64 + tid] = inv;
    invLds[tid] = inv;
    float ent = __logf(S) - W * inv;
#pragma unroll
    for (int off = 1; off < 64; off <<= 1) ent += __shfl_xor(ent, off, 64);
    if (tid == 0) atomicAdd(entAcc, ent);
  }
  __syncthreads();

  const int r = tid >> 2, cg = tid & 3;  // row, 16-col group
  float inv = invLds[r];
#pragma unroll
  for (int j = 0; j < 4; ++j) {
    int c = cg * 16 + j * 4;
    f32x4 s = (f32x4)0.0f;
#pragma unroll
    for (int ks = 0; ks < 4; ++ks)
      s += *(const f32x4*)(Opart + (size_t)(bx * 4 + ks) * 4096 + r * 64 + c);
    s *= inv;
    *(f32x4*)(out + ((size_t)bx * 64 + r) * 64 + c) = s;
  }
}

// ---------------------------------------------------------------------------
// Kernel 4: attn writer. Grid 8192 = (b, qtile 64, kchunk 32). Each WG:
// recompute scores for 64 q x 128 k, write attn = exp(s)*invS. Write-bound.
// ---------------------------------------------------------------------------
__global__ __launch_bounds__(256) void attn_write_kernel(
    const unsigned short* __restrict__ q_ws, const unsigned short* __restrict__ k_ws,
    const float* __restrict__ invS, float* __restrict__ attn) {
  __shared__ unsigned short Qs[64 * PITCH];
  __shared__ unsigned short Ks[128 * PITCH];
  __shared__ float invLds[64];

  const int tid = threadIdx.x;
  const int wave = tid >> 6, lane = tid & 63;
  const int quad = lane >> 4, l16 = lane & 15;
  const int bx = blockIdx.x;
  const int kc = bx & 31, qt = (bx >> 5) & 63, b = bx >> 11;
  const int q0 = qt * 64, k0g = kc * 128;

  const unsigned short* qb = q_ws + ((size_t)b * 4096 + q0) * 64;
  const unsigned short* kb = k_ws + ((size_t)b * 4096 + k0g) * 64;

#pragma unroll
  for (int i = 0; i < 2; ++i) {
    int cc = tid + i * 256;
    int row = cc >> 3, c8 = cc & 7;
    *(u16x8*)&Qs[row * PITCH + c8 * 8] = *(const u16x8*)(qb + (size_t)row * 64 + c8 * 8);
  }
#pragma unroll
  for (int i = 0; i < 4; ++i) {
    int cc = tid + i * 256;
    int row = cc >> 3, c8 = cc & 7;
    *(u16x8*)&Ks[row * PITCH + c8 * 8] = *(const u16x8*)(kb + (size_t)row * 64 + c8 * 8);
  }
  if (tid < 64) invLds[tid] = invS[(size_t)(b * 64 + qt) * 64 + tid];
  __syncthreads();

  f32x4 s[8];
#pragma unroll
  for (int i = 0; i < 8; ++i) s[i] = (f32x4)0.0f;
#pragma unroll
  for (int ks = 0; ks < 64; ks += 32) {
    bf16x8 a = *(const bf16x8*)&Qs[(wave * 16 + l16) * PITCH + ks + quad * 8];
#pragma unroll
    for (int nt = 0; nt < 8; ++nt) {
      bf16x8 bk = *(const bf16x8*)&Ks[(nt * 16 + l16) * PITCH + ks + quad * 8];
      s[nt] = mfma16(a, bk, s[nt]);
    }
  }

  float invR[4];
#pragma unroll
  for (int r = 0; r < 4; ++r) invR[r] = invLds[wave * 16 + quad * 4 + r];

  float* ab = attn + (size_t)b * 4096 * 4096;
#pragma unroll
  for (int nt = 0; nt < 8; ++nt)
#pragma unroll
    for (int r = 0; r < 4; ++r) {
      int m = q0 + wave * 16 + quad * 4 + r;
      ab[(size_t)m * 4096 + k0g + nt * 16 + l16] = __expf(s[nt][r]) * invR[r];
    }
}

// ---------------------------------------------------------------------------
// Kernel 5: new_energy = 0.9*energy + 0.1*mean_entropy
// ---------------------------------------------------------------------------
__global__ void energy_kernel(const float* __restrict__ energy,
                              const float* __restrict__ entAcc,
                              float* __restrict__ dst) {
  if (threadIdx.x == 0 && blockIdx.x == 0)
    dst[0] = 0.9f * energy[0] + 0.1f * (entAcc[0] * (1.0f / 16384.0f));
}

extern "C" void kernel_launch(void* const* d_in, const int* in_sizes, int n_in,
                              void* d_out, int out_size, void* d_ws, size_t ws_size,
                              hipStream_t stream) {
  (void)in_sizes; (void)n_in; (void)out_size; (void)ws_size;
  const float* x = (const float*)d_in[0];
  const float* Wq = (const float*)d_in[1];
  const float* Wk = (const float*)d_in[2];
  const float* Wv = (const float*)d_in[3];
  const float* energy = (const float*)d_in[4];

  float* out = (float*)d_out;                          // [4,4096,64]
  float* attn = out + (size_t)4 * 4096 * 64;           // [4,4096,4096]
  float* dst_energy = attn + (size_t)4 * 4096 * 4096;  // scalar

  char* ws = (char*)d_ws;
  float* entAcc = (float*)ws;                                   // 4 B (pad 256)
  unsigned short* q_ws = (unsigned short*)(ws + 256);           // 2 MB
  unsigned short* k_ws = q_ws + (size_t)16384 * 64;             // 2 MB
  unsigned short* vT_ws = k_ws + (size_t)16384 * 64;            // 2 MB
  float* invS = (float*)(vT_ws + (size_t)16384 * 64);           // 64 KB
  float* Spart = invS + 16384;                                  // 256 KB
  float* Wpart = Spart + 1024 * 64;                             // 256 KB
  float* Opart = Wpart + 1024 * 64;                             // 16 MB

  hipMemsetAsync(entAcc, 0, sizeof(float), stream);
  qkv_kernel<<<768, 256, 0, stream>>>(x, Wq, Wk, Wv, q_ws, k_ws, vT_ws);
  flash_kernel<<<1024, 256, 0, stream>>>(q_ws, k_ws, vT_ws, Opart, Spart, Wpart);
  combine_kernel<<<256, 256, 0, stream>>>(Opart, Spart, Wpart, out, invS, entAcc);
  attn_write_kernel<<<8192, 256, 0, stream>>>(q_ws, k_ws, invS, attn);
  energy_kernel<<<1, 64, 0, stream>>>(energy, entAcc, dst_energy);
}